// Round 3
// baseline (337.021 us; speedup 1.0000x reference)
//
#include <hip/hip_runtime.h>
#include <hip/hip_bf16.h>
#include <stdint.h>

typedef __attribute__((ext_vector_type(8))) short short8;
typedef __attribute__((ext_vector_type(8))) unsigned short ushort8;
typedef __attribute__((ext_vector_type(4))) float f32x4;

// col-tile (of 128) -> group id; group sizes/offsets
__constant__ int CT_GROUP[32] = {0,0,0,0, 1,1,1,1,1,1,1,1, 2,2, 3,3,3,3,3,3, 4,4,4, 5,5,5,5,5, 6, 7,7,7};
__constant__ int G_SIZE[8] = {512,1024,256,768,384,640,128,384};
__constant__ int G_OFF[8]  = {0,512,1536,1792,2560,2944,3584,3712};

__device__ __forceinline__ unsigned short f2bf(float f) {
    return __bfloat16_as_ushort(__float2bfloat16(f));
}

__global__ __launch_bounds__(256, 2) void cob_rot_kernel(
    const float* __restrict__ x,
    const float* __restrict__ w0, const float* __restrict__ w1,
    const float* __restrict__ w2, const float* __restrict__ w3,
    const float* __restrict__ w4, const float* __restrict__ w5,
    const float* __restrict__ w6, const float* __restrict__ w7,
    float* __restrict__ out)
{
    // 128x64 bf16 tiles, double buffered: 2*(16KB+16KB) = 64KB LDS
    __shared__ unsigned short As[2][128 * 64];
    __shared__ unsigned short Bs[2][128 * 64];

    const int bid = blockIdx.x;                 // 0..2047
    const int swz = ((bid & 7) << 8) | (bid >> 3);  // bijective XCD swizzle (2048 % 8 == 0)
    const int mtile = swz >> 5;                 // 0..63  (mtile-major inside an XCD chunk)
    const int ctile = swz & 31;                 // 0..31
    const int g = CT_GROUP[ctile];
    const int K = G_SIZE[g];
    const int koff = G_OFF[g];
    const float* W =
        (g == 0) ? w0 : (g == 1) ? w1 : (g == 2) ? w2 : (g == 3) ? w3 :
        (g == 4) ? w4 : (g == 5) ? w5 : (g == 6) ? w6 : w7;
    const int nlocal = (ctile << 7) - koff;     // row offset into W (output-col within group)
    const int mrow0 = mtile << 7;

    const int t = threadIdx.x;
    const int lane = t & 63;
    const int wid = t >> 6;
    const int wr = wid >> 1, wc = wid & 1;      // 2x2 wave grid, each wave 64x64 out

    // staging: thread t loads 8 contiguous fp32 per pass, 4 passes per operand
    const int sr = t >> 3;                      // 0..31
    const int sc = (t & 7) << 3;                // 0..56, step 8
    const int r7s = (sr & 7) << 3;              // row part of swizzle (p*32 doesn't change r&7)

    const float* Abase = x + (size_t)mrow0 * 4096 + koff;
    const float* Bbase = W + (size_t)nlocal * K;

    f32x4 acc[4][4] = {};

    float4 ra[8], rb[8];

    auto LOADREG = [&](int kbase) {
        #pragma unroll
        for (int p = 0; p < 4; ++p) {
            const float* pa = Abase + (size_t)(p * 32 + sr) * 4096 + (kbase + sc);
            ra[2 * p]     = *reinterpret_cast<const float4*>(pa);
            ra[2 * p + 1] = *reinterpret_cast<const float4*>(pa + 4);
            const float* pb = Bbase + (size_t)(p * 32 + sr) * K + (kbase + sc);
            rb[2 * p]     = *reinterpret_cast<const float4*>(pb);
            rb[2 * p + 1] = *reinterpret_cast<const float4*>(pb + 4);
        }
    };

    auto CVTWRITE = [&](int buf) {
        const int off = sr * 64 + (sc ^ r7s);   // swizzled element offset (16B aligned)
        #pragma unroll
        for (int p = 0; p < 4; ++p) {
            float4 a0 = ra[2 * p], a1 = ra[2 * p + 1];
            float4 b0 = rb[2 * p], b1 = rb[2 * p + 1];
            ushort8 va, vb;
            va[0] = f2bf(a0.x); va[1] = f2bf(a0.y); va[2] = f2bf(a0.z); va[3] = f2bf(a0.w);
            va[4] = f2bf(a1.x); va[5] = f2bf(a1.y); va[6] = f2bf(a1.z); va[7] = f2bf(a1.w);
            vb[0] = f2bf(b0.x); vb[1] = f2bf(b0.y); vb[2] = f2bf(b0.z); vb[3] = f2bf(b0.w);
            vb[4] = f2bf(b1.x); vb[5] = f2bf(b1.y); vb[6] = f2bf(b1.z); vb[7] = f2bf(b1.w);
            *reinterpret_cast<ushort8*>(&As[buf][p * 32 * 64 + off]) = va;
            *reinterpret_cast<ushort8*>(&Bs[buf][p * 32 * 64 + off]) = vb;
        }
    };

    const int NT = K >> 6;
    LOADREG(0);
    CVTWRITE(0);
    __syncthreads();

    int cur = 0;
    for (int kt = 0; kt < NT; ++kt) {
        const bool more = (kt + 1 < NT);
        if (more) LOADREG((kt + 1) << 6);       // global loads in flight across compute

        #pragma unroll
        for (int ks = 0; ks < 2; ++ks) {
            short8 af[4], bfr[4];
            const int chi = (ks << 5) + ((lane >> 4) << 3);  // k-slice column (element units)
            #pragma unroll
            for (int mi = 0; mi < 4; ++mi) {
                const int r = (wr << 6) + (mi << 4) + (lane & 15);
                af[mi] = *reinterpret_cast<const short8*>(&As[cur][r * 64 + (chi ^ ((r & 7) << 3))]);
            }
            #pragma unroll
            for (int ni = 0; ni < 4; ++ni) {
                const int r = (wc << 6) + (ni << 4) + (lane & 15);
                bfr[ni] = *reinterpret_cast<const short8*>(&Bs[cur][r * 64 + (chi ^ ((r & 7) << 3))]);
            }
            #pragma unroll
            for (int mi = 0; mi < 4; ++mi)
                #pragma unroll
                for (int ni = 0; ni < 4; ++ni)
                    acc[mi][ni] = __builtin_amdgcn_mfma_f32_16x16x32_bf16(af[mi], bfr[ni], acc[mi][ni], 0, 0, 0);
        }

        __syncthreads();                        // everyone done reading buf[cur]
        if (more) {
            CVTWRITE(cur ^ 1);                  // vmcnt drains here, not before compute
            __syncthreads();                    // tile kt+1 visible
        }
        cur ^= 1;
    }

    // epilogue: C/D layout col=lane&15, row=(lane>>4)*4+j  [m89/m91 verified]
    float* Cbase = out + (size_t)mrow0 * 4096 + (ctile << 7);
    const int cl = lane & 15;
    const int rbase = (lane >> 4) << 2;
    #pragma unroll
    for (int mi = 0; mi < 4; ++mi) {
        #pragma unroll
        for (int ni = 0; ni < 4; ++ni) {
            #pragma unroll
            for (int j = 0; j < 4; ++j) {
                const int row = (wr << 6) + (mi << 4) + rbase + j;
                const int col = (wc << 6) + (ni << 4) + cl;
                Cbase[(size_t)row * 4096 + col] = acc[mi][ni][j];
            }
        }
    }
}

extern "C" void kernel_launch(void* const* d_in, const int* in_sizes, int n_in,
                              void* d_out, int out_size, void* d_ws, size_t ws_size,
                              hipStream_t stream) {
    const float* x  = (const float*)d_in[0];
    const float* w0 = (const float*)d_in[1];
    const float* w1 = (const float*)d_in[2];
    const float* w2 = (const float*)d_in[3];
    const float* w3 = (const float*)d_in[4];
    const float* w4 = (const float*)d_in[5];
    const float* w5 = (const float*)d_in[6];
    const float* w6 = (const float*)d_in[7];
    const float* w7 = (const float*)d_in[8];
    float* out = (float*)d_out;

    dim3 grid(2048), block(256);
    cob_rot_kernel<<<grid, block, 0, stream>>>(x, w0, w1, w2, w3, w4, w5, w6, w7, out);
}

// Round 4
// 320.886 us; speedup vs baseline: 1.0503x; 1.0503x over previous
//
#include <hip/hip_runtime.h>
#include <hip/hip_bf16.h>
#include <stdint.h>

typedef __attribute__((ext_vector_type(8))) short short8;
typedef __attribute__((ext_vector_type(8))) unsigned short ushort8;
typedef __attribute__((ext_vector_type(4))) float f32x4;

__constant__ int CT_GROUP[32] = {0,0,0,0, 1,1,1,1,1,1,1,1, 2,2, 3,3,3,3,3,3, 4,4,4, 5,5,5,5,5, 6, 7,7,7};
// column tiles ordered by descending K (LPT scheduling of the tail)
__constant__ int CT_PERM[32] = {4,5,6,7,8,9,10,11, 14,15,16,17,18,19, 23,24,25,26,27, 0,1,2,3, 20,21,22, 29,30,31, 12,13, 28};
__constant__ int G_SIZE[8] = {512,1024,256,768,384,640,128,384};
__constant__ int G_OFF[8]  = {0,512,1536,1792,2560,2944,3584,3712};
// cumulative s_i^2 (elements) — offsets of each group inside wb
__constant__ int G_CUME[9] = {0,262144,1310720,1376256,1966080,2113536,2523136,2539520,2686976};

#define WB_ELEMS 2686976
#define WB_BYTES (WB_ELEMS * 2)

__device__ __forceinline__ unsigned short f2bf(float f) {
    return __bfloat16_as_ushort(__float2bfloat16(f));
}

__device__ __forceinline__ void gload16(const void* g, void* l) {
    __builtin_amdgcn_global_load_lds(
        (__attribute__((address_space(1))) void*)g,
        (__attribute__((address_space(3))) void*)l, 16, 0, 0);
}

// ---------------- kernel 1: convert W (fp32 -> bf16, linear concat) ----------
__global__ __launch_bounds__(256) void cvt_w_kernel(
    const float* __restrict__ w0, const float* __restrict__ w1,
    const float* __restrict__ w2, const float* __restrict__ w3,
    const float* __restrict__ w4, const float* __restrict__ w5,
    const float* __restrict__ w6, const float* __restrict__ w7,
    unsigned short* __restrict__ wb)
{
    const int gid = blockIdx.x * 256 + threadIdx.x;   // 1312*256 threads, exact
    const int e = gid * 8;
    int g = 0;
    #pragma unroll
    for (int i = 0; i < 7; ++i) g += (e >= G_CUME[i + 1]);
    const float* W =
        (g == 0) ? w0 : (g == 1) ? w1 : (g == 2) ? w2 : (g == 3) ? w3 :
        (g == 4) ? w4 : (g == 5) ? w5 : (g == 6) ? w6 : w7;
    const int local = e - G_CUME[g];
    float4 q0 = *reinterpret_cast<const float4*>(W + local);
    float4 q1 = *reinterpret_cast<const float4*>(W + local + 4);
    ushort8 v;
    v[0] = f2bf(q0.x); v[1] = f2bf(q0.y); v[2] = f2bf(q0.z); v[3] = f2bf(q0.w);
    v[4] = f2bf(q1.x); v[5] = f2bf(q1.y); v[6] = f2bf(q1.z); v[7] = f2bf(q1.w);
    *reinterpret_cast<ushort8*>(wb + e) = v;          // concat offset == e
}

// ---------------- kernel 2: grouped GEMM, gload_lds + BK=32 dbuf -------------
__global__ __launch_bounds__(256, 3) void cob_gemm_kernel(
    const float* __restrict__ x, const unsigned short* __restrict__ wb,
    float* __restrict__ out)
{
    // A: fp32 [128][32] = 16KB ; B: bf16 [128][32] = 8KB ; double buffered = 48KB
    __shared__ __attribute__((aligned(16))) uint8_t As[2][16384];
    __shared__ __attribute__((aligned(16))) uint8_t Bs[2][8192];

    const int bid = blockIdx.x;
    const int swz = ((bid & 7) << 8) | (bid >> 3);    // bijective XCD swizzle
    const int mtile = swz >> 5;
    const int ctile = CT_PERM[swz & 31];              // long-K ctiles first
    const int g = CT_GROUP[ctile];
    const int K = G_SIZE[g];
    const int koff = G_OFF[g];
    const int nlocal = (ctile << 7) - koff;
    const int mrow0 = mtile << 7;

    const int t = threadIdx.x;
    const int lane = t & 63;
    const int wid = t >> 6;
    const int wr = wid >> 1, wc = wid & 1;            // 2x2 waves, 64x64 out each

    // ---- per-lane staging addresses (rule #21: LDS linear, source XOR-swizzled)
    const uint8_t* xb = (const uint8_t*)x + (size_t)koff * 4;
    const uint8_t* wgb = (const uint8_t*)(wb + G_CUME[g]);
    const int wrow_bytes = K * 2;

    const uint8_t* srcA[4]; uint32_t ldsA[4];
    #pragma unroll
    for (int i = 0; i < 4; ++i) {
        const int j = wid * 4 + i;                    // 16 x 1KB instrs cover A tile
        const int row = 8 * j + (lane >> 3);
        srcA[i] = xb + (size_t)(mrow0 + row) * 16384
                     + ((((lane & 7) << 4) ^ ((row & 7) << 4)));
        ldsA[i] = j * 1024;
    }
    const uint8_t* srcB[2]; uint32_t ldsB[2];
    #pragma unroll
    for (int i = 0; i < 2; ++i) {
        const int j = wid * 2 + i;                    // 8 x 1KB instrs cover B tile
        const int R = 8 * j + (lane >> 3);            // 128B-row index
        const int q = (lane & 7) << 4;
        const int S = ((lane >> 3) & 7) << 4;
        const int qs = q ^ S;
        const int n = 2 * R + ((qs >> 6) & 1);        // paired-row layout
        const int k2 = qs & 63;
        srcB[i] = wgb + (size_t)(nlocal + n) * wrow_bytes + k2;
        ldsB[i] = j * 1024;
    }

    f32x4 acc[4][4] = {};

    auto STAGE = [&](int buf, int kt) {
        const size_t ka = (size_t)kt * 128;           // 32 fp32
        const size_t kb = (size_t)kt * 64;            // 32 bf16
        #pragma unroll
        for (int i = 0; i < 4; ++i) gload16(srcA[i] + ka, &As[buf][ldsA[i]]);
        #pragma unroll
        for (int i = 0; i < 2; ++i) gload16(srcB[i] + kb, &Bs[buf][ldsB[i]]);
    };

    auto COMPUTE = [&](int buf) {
        const uint8_t* Ab = As[buf];
        const uint8_t* Bb = Bs[buf];
        short8 af[4], bfr[4];
        #pragma unroll
        for (int mi = 0; mi < 4; ++mi) {
            const int r = (wr << 6) + (mi << 4) + (lane & 15);
            const int sw = (r & 7) << 4;
            const int c0 = (lane >> 4) << 5;          // byte col of 8 fp32
            float4 q0 = *reinterpret_cast<const float4*>(Ab + r * 128 + (c0 ^ sw));
            float4 q1 = *reinterpret_cast<const float4*>(Ab + r * 128 + ((c0 + 16) ^ sw));
            short8 v;
            v[0] = (short)f2bf(q0.x); v[1] = (short)f2bf(q0.y);
            v[2] = (short)f2bf(q0.z); v[3] = (short)f2bf(q0.w);
            v[4] = (short)f2bf(q1.x); v[5] = (short)f2bf(q1.y);
            v[6] = (short)f2bf(q1.z); v[7] = (short)f2bf(q1.w);
            af[mi] = v;
        }
        #pragma unroll
        for (int ni = 0; ni < 4; ++ni) {
            const int r = (wc << 6) + (ni << 4) + (lane & 15);
            const int q = ((r & 1) << 6) + ((lane >> 4) << 4);
            const int addr = ((r >> 1) << 7) + (q ^ (((r >> 1) & 7) << 4));
            bfr[ni] = *reinterpret_cast<const short8*>(Bb + addr);
        }
        #pragma unroll
        for (int mi = 0; mi < 4; ++mi)
            #pragma unroll
            for (int ni = 0; ni < 4; ++ni)
                acc[mi][ni] = __builtin_amdgcn_mfma_f32_16x16x32_bf16(af[mi], bfr[ni], acc[mi][ni], 0, 0, 0);
    };

    const int NT = K >> 5;
    STAGE(0, 0);
    __syncthreads();                                  // drains vmcnt(0)
    int cur = 0;
    for (int kt = 0; kt < NT; ++kt) {
        if (kt + 1 < NT) STAGE(cur ^ 1, kt + 1);      // loads overlap compute
        COMPUTE(cur);
        __syncthreads();                              // one barrier per K-step
        cur ^= 1;
    }

    float* Cbase = out + (size_t)mrow0 * 4096 + (ctile << 7);
    const int cl = lane & 15;
    const int rbase = (lane >> 4) << 2;
    #pragma unroll
    for (int mi = 0; mi < 4; ++mi)
        #pragma unroll
        for (int ni = 0; ni < 4; ++ni)
            #pragma unroll
            for (int j = 0; j < 4; ++j) {
                const int row = (wr << 6) + (mi << 4) + rbase + j;
                const int col = (wc << 6) + (ni << 4) + cl;
                Cbase[(size_t)row * 4096 + col] = acc[mi][ni][j];
            }
}

// ---------------- fallback (round-3 kernel, proven correct) ------------------
__global__ __launch_bounds__(256, 2) void cob_rot_fallback(
    const float* __restrict__ x,
    const float* __restrict__ w0, const float* __restrict__ w1,
    const float* __restrict__ w2, const float* __restrict__ w3,
    const float* __restrict__ w4, const float* __restrict__ w5,
    const float* __restrict__ w6, const float* __restrict__ w7,
    float* __restrict__ out)
{
    __shared__ unsigned short As[2][128 * 64];
    __shared__ unsigned short Bs[2][128 * 64];
    const int bid = blockIdx.x;
    const int swz = ((bid & 7) << 8) | (bid >> 3);
    const int mtile = swz >> 5;
    const int ctile = swz & 31;
    const int g = CT_GROUP[ctile];
    const int K = G_SIZE[g];
    const int koff = G_OFF[g];
    const float* W =
        (g == 0) ? w0 : (g == 1) ? w1 : (g == 2) ? w2 : (g == 3) ? w3 :
        (g == 4) ? w4 : (g == 5) ? w5 : (g == 6) ? w6 : w7;
    const int nlocal = (ctile << 7) - koff;
    const int mrow0 = mtile << 7;
    const int t = threadIdx.x;
    const int lane = t & 63;
    const int wid = t >> 6;
    const int wr = wid >> 1, wc = wid & 1;
    const int sr = t >> 3;
    const int sc = (t & 7) << 3;
    const int r7s = (sr & 7) << 3;
    const float* Abase = x + (size_t)mrow0 * 4096 + koff;
    const float* Bbase = W + (size_t)nlocal * K;
    f32x4 acc[4][4] = {};
    float4 ra[8], rb[8];
    auto LOADREG = [&](int kbase) {
        #pragma unroll
        for (int p = 0; p < 4; ++p) {
            const float* pa = Abase + (size_t)(p * 32 + sr) * 4096 + (kbase + sc);
            ra[2 * p] = *reinterpret_cast<const float4*>(pa);
            ra[2 * p + 1] = *reinterpret_cast<const float4*>(pa + 4);
            const float* pb = Bbase + (size_t)(p * 32 + sr) * K + (kbase + sc);
            rb[2 * p] = *reinterpret_cast<const float4*>(pb);
            rb[2 * p + 1] = *reinterpret_cast<const float4*>(pb + 4);
        }
    };
    auto CVTWRITE = [&](int buf) {
        const int off = sr * 64 + (sc ^ r7s);
        #pragma unroll
        for (int p = 0; p < 4; ++p) {
            float4 a0 = ra[2 * p], a1 = ra[2 * p + 1];
            float4 b0 = rb[2 * p], b1 = rb[2 * p + 1];
            ushort8 va, vb;
            va[0] = f2bf(a0.x); va[1] = f2bf(a0.y); va[2] = f2bf(a0.z); va[3] = f2bf(a0.w);
            va[4] = f2bf(a1.x); va[5] = f2bf(a1.y); va[6] = f2bf(a1.z); va[7] = f2bf(a1.w);
            vb[0] = f2bf(b0.x); vb[1] = f2bf(b0.y); vb[2] = f2bf(b0.z); vb[3] = f2bf(b0.w);
            vb[4] = f2bf(b1.x); vb[5] = f2bf(b1.y); vb[6] = f2bf(b1.z); vb[7] = f2bf(b1.w);
            *reinterpret_cast<ushort8*>(&As[buf][p * 32 * 64 + off]) = va;
            *reinterpret_cast<ushort8*>(&Bs[buf][p * 32 * 64 + off]) = vb;
        }
    };
    const int NT = K >> 6;
    LOADREG(0); CVTWRITE(0);
    __syncthreads();
    int cur = 0;
    for (int kt = 0; kt < NT; ++kt) {
        const bool more = (kt + 1 < NT);
        if (more) LOADREG((kt + 1) << 6);
        #pragma unroll
        for (int ks = 0; ks < 2; ++ks) {
            short8 af[4], bfr[4];
            const int chi = (ks << 5) + ((lane >> 4) << 3);
            #pragma unroll
            for (int mi = 0; mi < 4; ++mi) {
                const int r = (wr << 6) + (mi << 4) + (lane & 15);
                af[mi] = *reinterpret_cast<const short8*>(&As[cur][r * 64 + (chi ^ ((r & 7) << 3))]);
            }
            #pragma unroll
            for (int ni = 0; ni < 4; ++ni) {
                const int r = (wc << 6) + (ni << 4) + (lane & 15);
                bfr[ni] = *reinterpret_cast<const short8*>(&Bs[cur][r * 64 + (chi ^ ((r & 7) << 3))]);
            }
            #pragma unroll
            for (int mi = 0; mi < 4; ++mi)
                #pragma unroll
                for (int ni = 0; ni < 4; ++ni)
                    acc[mi][ni] = __builtin_amdgcn_mfma_f32_16x16x32_bf16(af[mi], bfr[ni], acc[mi][ni], 0, 0, 0);
        }
        __syncthreads();
        if (more) { CVTWRITE(cur ^ 1); __syncthreads(); }
        cur ^= 1;
    }
    float* Cbase = out + (size_t)mrow0 * 4096 + (ctile << 7);
    const int cl = lane & 15;
    const int rbase = (lane >> 4) << 2;
    #pragma unroll
    for (int mi = 0; mi < 4; ++mi)
        #pragma unroll
        for (int ni = 0; ni < 4; ++ni)
            #pragma unroll
            for (int j = 0; j < 4; ++j) {
                const int row = (wr << 6) + (mi << 4) + rbase + j;
                const int col = (wc << 6) + (ni << 4) + cl;
                Cbase[(size_t)row * 4096 + col] = acc[mi][ni][j];
            }
}

extern "C" void kernel_launch(void* const* d_in, const int* in_sizes, int n_in,
                              void* d_out, int out_size, void* d_ws, size_t ws_size,
                              hipStream_t stream) {
    const float* x  = (const float*)d_in[0];
    const float* w0 = (const float*)d_in[1];
    const float* w1 = (const float*)d_in[2];
    const float* w2 = (const float*)d_in[3];
    const float* w3 = (const float*)d_in[4];
    const float* w4 = (const float*)d_in[5];
    const float* w5 = (const float*)d_in[6];
    const float* w6 = (const float*)d_in[7];
    const float* w7 = (const float*)d_in[8];
    float* out = (float*)d_out;

    if (ws_size >= (size_t)WB_BYTES + 256) {
        unsigned short* wb = (unsigned short*)d_ws;
        cvt_w_kernel<<<dim3(1312), dim3(256), 0, stream>>>(w0, w1, w2, w3, w4, w5, w6, w7, wb);
        cob_gemm_kernel<<<dim3(2048), dim3(256), 0, stream>>>(x, wb, out);
    } else {
        cob_rot_fallback<<<dim3(2048), dim3(256), 0, stream>>>(x, w0, w1, w2, w3, w4, w5, w6, w7, out);
    }
}